// Round 2
// baseline (1066.041 us; speedup 1.0000x reference)
//
#include <hip/hip_runtime.h>
#include <cmath>

#define DIM 1024
#define DIM_INNER 2048
#define BATCH 4
#define SEQ 4096
#define CHUNK 64
#define NCHUNK (SEQ / CHUNK)        // 64 chunks per sequence

typedef __bf16 bf16x8 __attribute__((ext_vector_type(8)));
typedef short short8_t __attribute__((ext_vector_type(8)));
typedef float floatx4 __attribute__((ext_vector_type(4)));

__device__ __forceinline__ unsigned short f2bf(float f) {
  unsigned int u = __builtin_bit_cast(unsigned int, f);
  u += 0x7fffu + ((u >> 16) & 1u);   // round-to-nearest-even
  return (unsigned short)(u >> 16);
}
__device__ __forceinline__ float bflo2f(unsigned int u) {
  return __builtin_bit_cast(float, u << 16);
}
__device__ __forceinline__ float bfhi2f(unsigned int u) {
  return __builtin_bit_cast(float, u & 0xffff0000u);
}

__device__ __forceinline__ float softplus_f(float x) {
  return fmaxf(x, 0.0f) + log1pf(expf(-fabsf(x)));
}
// log_g: x>=0 -> log(x+0.5); x<0 -> -softplus(-x) = x - log1p(exp(x))
__device__ __forceinline__ float log_g_f(float h) {
  return (h >= 0.0f) ? logf(h + 0.5f) : (h - log1pf(expf(h)));
}
// b finite; a may be -inf
__device__ __forceinline__ float logaddexp_f(float a, float b) {
  float m = fmaxf(a, b);
  return m + log1pf(expf(-fabsf(a - b)));
}

// ---------------------------------------------------------------------------
// GEMM1 fused: hg = X @ W_hg; hidden=cols[0,2048), gate=cols[2048,4096).
// 64x64 hidden tile + matching gate tile (shared A tile); epilogue packs
// (LC,LV) as two bf16 into one uint32 per element.
// Rows = nrows (a whole number of batches); X/LCLV pointers pre-offset.
// ---------------------------------------------------------------------------
__global__ __launch_bounds__(256) void gemm1_fused(
    const float* __restrict__ X, const float* __restrict__ W,
    unsigned int* __restrict__ LCLV) {
  __shared__ __align__(16) unsigned short As[64][32];
  __shared__ __align__(16) unsigned short Bh[32][64];
  __shared__ __align__(16) unsigned short Bg[32][64];

  const int tid = threadIdx.x;
  const int n0 = blockIdx.x * 64;   // inner-dim column 0..2047
  const int m0 = blockIdx.y * 64;   // row

  const int wave = tid >> 6;
  const int lane = tid & 63;
  const int wm = (wave >> 1) * 32;
  const int wn = (wave & 1) * 32;
  const int l15 = lane & 15;
  const int quad = lane >> 4;

  floatx4 acch[2][2], accg[2][2];
#pragma unroll
  for (int i = 0; i < 2; i++)
#pragma unroll
    for (int j = 0; j < 2; j++) {
      acch[i][j] = (floatx4){0.f, 0.f, 0.f, 0.f};
      accg[i][j] = (floatx4){0.f, 0.f, 0.f, 0.f};
    }

  const int ar = tid >> 3, ac = (tid & 7) * 4;
  const int br = tid >> 4, bc = (tid & 15) * 4;

  for (int k0 = 0; k0 < DIM; k0 += 32) {
    __syncthreads();
#pragma unroll
    for (int p = 0; p < 2; p++) {
      int r = ar + p * 32;
      float4 v = *(const float4*)(X + (size_t)(m0 + r) * DIM + k0 + ac);
      As[r][ac + 0] = f2bf(v.x); As[r][ac + 1] = f2bf(v.y);
      As[r][ac + 2] = f2bf(v.z); As[r][ac + 3] = f2bf(v.w);
    }
#pragma unroll
    for (int p = 0; p < 2; p++) {
      int r = br + p * 16;
      const float* wrow = W + (size_t)(k0 + r) * (2 * DIM_INNER);
      float4 vh = *(const float4*)(wrow + n0 + bc);
      float4 vg = *(const float4*)(wrow + DIM_INNER + n0 + bc);
      Bh[r][bc + 0] = f2bf(vh.x); Bh[r][bc + 1] = f2bf(vh.y);
      Bh[r][bc + 2] = f2bf(vh.z); Bh[r][bc + 3] = f2bf(vh.w);
      Bg[r][bc + 0] = f2bf(vg.x); Bg[r][bc + 1] = f2bf(vg.y);
      Bg[r][bc + 2] = f2bf(vg.z); Bg[r][bc + 3] = f2bf(vg.w);
    }
    __syncthreads();

    bf16x8 afr[2];
#pragma unroll
    for (int i = 0; i < 2; i++) {
      short8_t sv = *(const short8_t*)(&As[wm + i * 16 + l15][quad * 8]);
      afr[i] = __builtin_bit_cast(bf16x8, sv);
    }
    bf16x8 bhf[2], bgf[2];
#pragma unroll
    for (int j = 0; j < 2; j++) {
      short8_t th, tg;
      int col = wn + j * 16 + l15;
#pragma unroll
      for (int z = 0; z < 8; z++) {
        th[z] = (short)Bh[quad * 8 + z][col];
        tg[z] = (short)Bg[quad * 8 + z][col];
      }
      bhf[j] = __builtin_bit_cast(bf16x8, th);
      bgf[j] = __builtin_bit_cast(bf16x8, tg);
    }
#pragma unroll
    for (int i = 0; i < 2; i++)
#pragma unroll
      for (int j = 0; j < 2; j++) {
        acch[i][j] = __builtin_amdgcn_mfma_f32_16x16x32_bf16(afr[i], bhf[j], acch[i][j], 0, 0, 0);
        accg[i][j] = __builtin_amdgcn_mfma_f32_16x16x32_bf16(afr[i], bgf[j], accg[i][j], 0, 0, 0);
      }
  }

#pragma unroll
  for (int i = 0; i < 2; i++)
#pragma unroll
    for (int j = 0; j < 2; j++) {
      int col = n0 + wn + j * 16 + l15;
#pragma unroll
      for (int r = 0; r < 4; r++) {
        int row = m0 + wm + i * 16 + quad * 4 + r;
        float h = acch[i][j][r];
        float g = accg[i][j][r];
        float lc = -softplus_f(g);
        float lv = -softplus_f(-g) + log_g_f(h);
        unsigned int pk = ((unsigned int)f2bf(lv) << 16) | (unsigned int)f2bf(lc);
        LCLV[(size_t)row * DIM_INNER + col] = pk;
      }
    }
}

// ---------------------------------------------------------------------------
// Chunked log-space scan over s. nbch = nb*2048 channels in this pass.
// ---------------------------------------------------------------------------
__global__ __launch_bounds__(256) void scan_phase1(
    const unsigned int* __restrict__ LCLV,
    float* __restrict__ Asum, float* __restrict__ Lend, int nbch) {
  int tid = blockIdx.x * 256 + threadIdx.x;   // nb*2048*64
  int e = tid % DIM_INNER;
  int tmp = tid / DIM_INNER;
  int c = tmp % NCHUNK;
  int bz = tmp / NCHUNK;
  int ch = bz * DIM_INNER + e;
  size_t base = ((size_t)bz * SEQ + (size_t)c * CHUNK) * DIM_INNER + e;
  float asum = 0.f, logh = -INFINITY;
  for (int t = 0; t < CHUNK; t++) {
    unsigned int u = LCLV[base + (size_t)t * DIM_INNER];
    float lc = bflo2f(u), lv = bfhi2f(u);
    asum += lc;
    logh = logaddexp_f(lc + logh, lv);
  }
  Asum[(size_t)c * nbch + ch] = asum;
  Lend[(size_t)c * nbch + ch] = logh;
}

__global__ __launch_bounds__(256) void scan_phase2(
    const float* __restrict__ Asum, const float* __restrict__ Lend,
    float* __restrict__ P, int nbch) {
  int ch = blockIdx.x * 256 + threadIdx.x;    // nbch
  float p = -INFINITY;
  for (int c = 0; c < NCHUNK; c++) {
    P[(size_t)c * nbch + ch] = p;             // prefix BEFORE chunk c
    float a = Asum[(size_t)c * nbch + ch];
    float le = Lend[(size_t)c * nbch + ch];
    p = logaddexp_f(a + p, le);
  }
}

// Rescan with real prefix; overwrite each packed slot with fp32 h in place.
__global__ __launch_bounds__(256) void scan_phase3(
    unsigned int* __restrict__ LCLV, const float* __restrict__ P, int nbch) {
  int tid = blockIdx.x * 256 + threadIdx.x;
  int e = tid % DIM_INNER;
  int tmp = tid / DIM_INNER;
  int c = tmp % NCHUNK;
  int bz = tmp / NCHUNK;
  int ch = bz * DIM_INNER + e;
  size_t base = ((size_t)bz * SEQ + (size_t)c * CHUNK) * DIM_INNER + e;
  float logh = P[(size_t)c * nbch + ch];
  for (int t = 0; t < CHUNK; t++) {
    size_t idx = base + (size_t)t * DIM_INNER;
    unsigned int u = LCLV[idx];
    float lc = bflo2f(u), lv = bfhi2f(u);
    logh = logaddexp_f(lc + logh, lv);
    ((float*)LCLV)[idx] = expf(logh);
  }
}

// ---------------------------------------------------------------------------
// GEMM2: out = H @ W_out   (nrows x 2048) @ (2048 x 1024), H fp32 in ws
// ---------------------------------------------------------------------------
__global__ __launch_bounds__(256) void gemm2(
    const float* __restrict__ H, const float* __restrict__ W,
    float* __restrict__ OUT) {
  __shared__ __align__(16) unsigned short As[64][32];
  __shared__ __align__(16) unsigned short Bs[32][64];

  const int tid = threadIdx.x;
  const int n0 = blockIdx.x * 64;
  const int m0 = blockIdx.y * 64;

  const int wave = tid >> 6;
  const int lane = tid & 63;
  const int wm = (wave >> 1) * 32;
  const int wn = (wave & 1) * 32;
  const int l15 = lane & 15;
  const int quad = lane >> 4;

  floatx4 acc[2][2];
#pragma unroll
  for (int i = 0; i < 2; i++)
#pragma unroll
    for (int j = 0; j < 2; j++) acc[i][j] = (floatx4){0.f, 0.f, 0.f, 0.f};

  const int ar = tid >> 3, ac = (tid & 7) * 4;
  const int br = tid >> 4, bc = (tid & 15) * 4;

  for (int k0 = 0; k0 < DIM_INNER; k0 += 32) {
    __syncthreads();
#pragma unroll
    for (int p = 0; p < 2; p++) {
      int r = ar + p * 32;
      float4 v = *(const float4*)(H + (size_t)(m0 + r) * DIM_INNER + k0 + ac);
      As[r][ac + 0] = f2bf(v.x); As[r][ac + 1] = f2bf(v.y);
      As[r][ac + 2] = f2bf(v.z); As[r][ac + 3] = f2bf(v.w);
    }
    {
      int r = br;
      float4 v = *(const float4*)(W + (size_t)(k0 + r) * DIM + n0 + bc);
      Bs[r][bc + 0] = f2bf(v.x); Bs[r][bc + 1] = f2bf(v.y);
      Bs[r][bc + 2] = f2bf(v.z); Bs[r][bc + 3] = f2bf(v.w);
      r = br + 16;
      v = *(const float4*)(W + (size_t)(k0 + r) * DIM + n0 + bc);
      Bs[r][bc + 0] = f2bf(v.x); Bs[r][bc + 1] = f2bf(v.y);
      Bs[r][bc + 2] = f2bf(v.z); Bs[r][bc + 3] = f2bf(v.w);
    }
    __syncthreads();

    bf16x8 afr[2];
#pragma unroll
    for (int i = 0; i < 2; i++) {
      short8_t sv = *(const short8_t*)(&As[wm + i * 16 + l15][quad * 8]);
      afr[i] = __builtin_bit_cast(bf16x8, sv);
    }
    bf16x8 bfr[2];
#pragma unroll
    for (int j = 0; j < 2; j++) {
      short8_t tb;
      int col = wn + j * 16 + l15;
#pragma unroll
      for (int z = 0; z < 8; z++) tb[z] = (short)Bs[quad * 8 + z][col];
      bfr[j] = __builtin_bit_cast(bf16x8, tb);
    }
#pragma unroll
    for (int i = 0; i < 2; i++)
#pragma unroll
      for (int j = 0; j < 2; j++)
        acc[i][j] = __builtin_amdgcn_mfma_f32_16x16x32_bf16(afr[i], bfr[j], acc[i][j], 0, 0, 0);
  }

#pragma unroll
  for (int i = 0; i < 2; i++)
#pragma unroll
    for (int j = 0; j < 2; j++) {
      int col = n0 + wn + j * 16 + l15;
#pragma unroll
      for (int r = 0; r < 4; r++) {
        int row = m0 + wm + i * 16 + quad * 4 + r;
        OUT[(size_t)row * DIM + col] = acc[i][j][r];
      }
    }
}

extern "C" void kernel_launch(void* const* d_in, const int* in_sizes, int n_in,
                              void* d_out, int out_size, void* d_ws, size_t ws_size,
                              hipStream_t stream) {
  const float* X = (const float*)d_in[0];     // [4,4096,1024]
  const float* Whg = (const float*)d_in[1];   // [1024,4096]
  const float* Wout = (const float*)d_in[2];  // [2048,1024]
  float* out = (float*)d_out;                 // [4,4096,1024] fp32

  // Per-batch footprint: packed LCLV 4096*2048*4B = 33.55 MB
  //                    + 3 summaries of 2048*64*4B = 1.5 MB
  const size_t pack_elems_b = (size_t)SEQ * DIM_INNER;           // per batch
  const size_t summ_elems_b = (size_t)DIM_INNER * NCHUNK;        // per batch
  const size_t per_batch_bytes = pack_elems_b * 4 + 3 * summ_elems_b * 4;

  // Deterministic pass sizing from ws_size (same every call).
  int nb = 4;
  while (nb > 1 && (size_t)nb * per_batch_bytes > ws_size) nb >>= 1;
  const int npass = BATCH / nb;

  for (int pass = 0; pass < npass; pass++) {
    const int b0 = pass * nb;
    const int nrows = nb * SEQ;
    const int nbch = nb * DIM_INNER;

    unsigned int* LCLV = (unsigned int*)d_ws;
    float* Asum = (float*)(LCLV + (size_t)nb * pack_elems_b);
    float* Lend = Asum + (size_t)nb * summ_elems_b;
    float* P = Lend + (size_t)nb * summ_elems_b;

    const float* Xp = X + (size_t)b0 * SEQ * DIM;
    float* outp = out + (size_t)b0 * SEQ * DIM;

    gemm1_fused<<<dim3(DIM_INNER / 64, nrows / 64), 256, 0, stream>>>(Xp, Whg, LCLV);
    scan_phase1<<<(nbch * NCHUNK) / 256, 256, 0, stream>>>(LCLV, Asum, Lend, nbch);
    scan_phase2<<<nbch / 256, 256, 0, stream>>>(Asum, Lend, P, nbch);
    scan_phase3<<<(nbch * NCHUNK) / 256, 256, 0, stream>>>(LCLV, P, nbch);
    gemm2<<<dim3(DIM / 64, nrows / 64), 256, 0, stream>>>((const float*)LCLV, Wout, outp);
  }
}